// Round 22
// baseline (280338.379 us; speedup 1.0000x reference)
//
#include <hip/hip_runtime.h>
#include <stdint.h>

typedef unsigned long long u64;
typedef unsigned int u32;
typedef u32   u32x4  __attribute__((ext_vector_type(4)));
typedef float f32x16 __attribute__((ext_vector_type(16)));
typedef float f32x8  __attribute__((ext_vector_type(8)));
typedef float f32x4  __attribute__((ext_vector_type(4)));

#define T_TOTAL 65536
#define ISZ 256
#define HSZ 512
#define NWORK 32   // 32 blocks on ONE XCD (1 per CU)
#define SLICE 16   // units per block
#define NTHR 512

// x_lds skew: rows of 8 words, +4 pad -> 12-word stride (4-way max conflict).
__device__ __forceinline__ int XS2(int i) { return i + ((i >> 3) << 2); }
// slow-path h skew (rows of 16, +4)
__device__ __forceinline__ int HS2(int i) { return i + ((i >> 4) << 2); }

struct Ctl { int grank; int chosen; int fastctr; int done; int slowctr; int pad[11]; };

__device__ __forceinline__ f32x4 xload_asm(const float* p) {
  f32x4 r;
  asm volatile("global_load_dwordx4 %0, %1, off" : "=v"(r) : "v"(p));
  return r;
}

// ---------------------------------------------------------------------------
// Persistent fused GRU scan — BARRIER-FREE dataflow, FULL 32-bit tags.
//
// R21 failed on 2-bit tag aliasing (stale line >=4 versions old gives a false
// positive). Fix: {tag32,val32} 8B pairs. To keep poll-as-fetch one 128B line
// per thread, re-tile: 32 blocks x 512 thr; block owns 16 units; K split in
// 32 segs of 16. Thread (kseg=tid&31, urg=tid>>5) polls block kseg's line
// (16 pairs, 8 dwordx4 in flight, one vmcnt(0)) straight into registers.
// Full tag => staleness can only cause re-polls, never corruption.
//
// Progress/overwrite induction (no barrier): version s+2 (bank s&1) appears
// only after its publisher detected ALL of s+1, which requires every wave
// (each wave's 64 lanes poll all 32 lines = all 512 units) to have published
// s+1, i.e. finished step s (incl. its MACC reads of version s from regs).
// Hence a lane still polling version s can never see its bank overwritten.
// Wave skew <= 1 step.
//
// x staging: wave 0 commits x[s+2] into x_lds[(s+2)&3] (reg loaded 2 steps
// ago, drained by this step's vmcnt(0)), fenced by lgkmcnt(0) BEFORE wave-0
// publisher lanes' version-(s+1) store. A reader's step-(s+2) ig-dots follow
// its detection of version s+1 (incl. wave-0's units) => commit visible.
// 4 banks cover skew +-1. hold = publisher's hprev register.
//
// Poll: nt+sc0 L2 loads (R20-proven eventually-coherent); sticky buffer_inv
// round (R14-proven) if a step needs >=64 rounds; budget fuse (fail visibly).
// SLOW fallback (election < 32 same-XCD blocks): agent-scope full-tag
// protocol with barriers (R2-proven primitives, same tiling).
// ---------------------------------------------------------------------------
__global__ __launch_bounds__(NTHR, 1) void gru_fused(
    const float* __restrict__ xs, const float* __restrict__ w_ih,
    const float* __restrict__ w_hh, const float* __restrict__ bias,
    const float* __restrict__ bias_n, u64* __restrict__ hpack,
    Ctl* __restrict__ ctl, float* __restrict__ out) {
  const int tid  = threadIdx.x;
  const int kseg = tid & 31;   // K-segment: h[16*kseg..+16), x[8*kseg..+8)
  const int urg  = tid >> 5;   // unit within slice (0..15)

  __shared__ int s_role, s_fast;
  __shared__ __align__(16) float x_lds[4][384];
  __shared__ __align__(16) float h_slow[640];   // slow path only

  // ---- election: verify 32 blocks on one XCD, else agent-scope fallback
  if (tid == 0) {
    unsigned xcc = 0;
    asm volatile("s_getreg_b32 %0, hwreg(HW_REG_XCC_ID)" : "=s"(xcc));
    long long eb = 100000000;
    int rank = __hip_atomic_fetch_add(&ctl->grank, 1, __ATOMIC_RELAXED,
                                      __HIP_MEMORY_SCOPE_AGENT);
    if (rank == 0)
      __hip_atomic_store(&ctl->chosen, (int)xcc + 1, __ATOMIC_RELEASE,
                         __HIP_MEMORY_SCOPE_AGENT);
    int chosen;
    do { chosen = __hip_atomic_load(&ctl->chosen, __ATOMIC_ACQUIRE,
                                    __HIP_MEMORY_SCOPE_AGENT); }
    while (chosen == 0 && --eb > 0);
    int fr = -1;
    if ((int)xcc == chosen - 1)
      fr = __hip_atomic_fetch_add(&ctl->fastctr, 1, __ATOMIC_RELAXED,
                                  __HIP_MEMORY_SCOPE_AGENT);
    __hip_atomic_fetch_add(&ctl->done, 1, __ATOMIC_ACQ_REL,
                           __HIP_MEMORY_SCOPE_AGENT);
    int dn;
    do { dn = __hip_atomic_load(&ctl->done, __ATOMIC_ACQUIRE,
                                __HIP_MEMORY_SCOPE_AGENT); }
    while (dn < (int)gridDim.x && --eb > 0);
    int fc = __hip_atomic_load(&ctl->fastctr, __ATOMIC_ACQUIRE,
                               __HIP_MEMORY_SCOPE_AGENT);
    int fast = (fc >= NWORK && dn >= (int)gridDim.x) ? 1 : 0;
    int role = -1;
    if (fast) {
      if (fr >= 0 && fr < NWORK) role = fr;
    } else {
      int sr = __hip_atomic_fetch_add(&ctl->slowctr, 1, __ATOMIC_RELAXED,
                                      __HIP_MEMORY_SCOPE_AGENT);
      if (sr < NWORK) role = sr;
    }
    s_role = role; s_fast = fast;
  }
  __syncthreads();
  const int role = s_role;   // uniform per block
  const int fast = s_fast;
  if (role < 0) return;      // whole block exits together

  // ---- weights into registers: unit myunit, K-cols [16k..+16) / [8k..+8)
  const int myunit = role * SLICE + urg;
  f32x16 wh0, wh1, wh2;
  f32x8  wi0, wi1, wi2;
  {
    const float* h0 = w_hh + (size_t)(0 * HSZ + myunit) * HSZ + kseg * 16;
    const float* h1 = w_hh + (size_t)(1 * HSZ + myunit) * HSZ + kseg * 16;
    const float* h2 = w_hh + (size_t)(2 * HSZ + myunit) * HSZ + kseg * 16;
#pragma unroll
    for (int u = 0; u < 4; ++u) {
      float4 a = *(const float4*)(h0 + u * 4);
      float4 b = *(const float4*)(h1 + u * 4);
      float4 c = *(const float4*)(h2 + u * 4);
      wh0[u*4+0]=a.x; wh0[u*4+1]=a.y; wh0[u*4+2]=a.z; wh0[u*4+3]=a.w;
      wh1[u*4+0]=b.x; wh1[u*4+1]=b.y; wh1[u*4+2]=b.z; wh1[u*4+3]=b.w;
      wh2[u*4+0]=c.x; wh2[u*4+1]=c.y; wh2[u*4+2]=c.z; wh2[u*4+3]=c.w;
    }
    const float* i0 = w_ih + (size_t)(0 * HSZ + myunit) * ISZ + kseg * 8;
    const float* i1 = w_ih + (size_t)(1 * HSZ + myunit) * ISZ + kseg * 8;
    const float* i2 = w_ih + (size_t)(2 * HSZ + myunit) * ISZ + kseg * 8;
#pragma unroll
    for (int u = 0; u < 2; ++u) {
      float4 a = *(const float4*)(i0 + u * 4);
      float4 b = *(const float4*)(i1 + u * 4);
      float4 c = *(const float4*)(i2 + u * 4);
      wi0[u*4+0]=a.x; wi0[u*4+1]=a.y; wi0[u*4+2]=a.z; wi0[u*4+3]=a.w;
      wi1[u*4+0]=b.x; wi1[u*4+1]=b.y; wi1[u*4+2]=b.z; wi1[u*4+3]=b.w;
      wi2[u*4+0]=c.x; wi2[u*4+1]=c.y; wi2[u*4+2]=c.z; wi2[u*4+3]=c.w;
    }
  }
  const float br  = bias[myunit];
  const float bz  = bias[HSZ + myunit];
  const float bnn = bias[2 * HSZ + myunit];
  const float bn2 = bias_n[myunit];

  long long budget = 20000000;  // spin fuse (fail visibly, never wedge)
  float hprev = 0.f;            // kseg0 lanes: clean previous h of myunit

  if (!fast) {
    // ---- SLOW fallback: barrier-based, agent-scope, full-tag ----
    for (int s = 0; s < T_TOTAL; ++s) {
      if (tid < 64) {
        float4 v = *(const float4*)(xs + (size_t)s * ISZ + tid * 4);
        *(float4*)&x_lds[0][XS2(tid * 4)] = v;
      }
      __syncthreads();
      float a0 = 0.f, a1 = 0.f, a2 = 0.f, a3 = 0.f;
#pragma unroll
      for (int u = 0; u < 2; ++u) {
        float4 xv = *(const float4*)&x_lds[0][XS2(kseg * 8 + u * 4)];
        a0 += wi0[u*4+0]*xv.x + wi0[u*4+1]*xv.y + wi0[u*4+2]*xv.z + wi0[u*4+3]*xv.w;
        a1 += wi1[u*4+0]*xv.x + wi1[u*4+1]*xv.y + wi1[u*4+2]*xv.z + wi1[u*4+3]*xv.w;
        a2 += wi2[u*4+0]*xv.x + wi2[u*4+1]*xv.y + wi2[u*4+2]*xv.z + wi2[u*4+3]*xv.w;
      }
      const int cur = s & 1, nxt = cur ^ 1;
      u64 q;
      do {
        q = __hip_atomic_load(&hpack[(size_t)cur * HSZ + tid], __ATOMIC_ACQUIRE,
                              __HIP_MEMORY_SCOPE_AGENT);
      } while ((u32)q != (u32)s && --budget > 0);
      h_slow[HS2(tid)] = __uint_as_float((u32)(q >> 32));
      __syncthreads();
#pragma unroll
      for (int j = 0; j < 16; ++j) {
        float hv = h_slow[HS2(kseg * 16 + j)];
        a0 += wh0[j] * hv; a1 += wh1[j] * hv; a3 += wh2[j] * hv;
      }
#pragma unroll
      for (int p = 0; p < 5; ++p) {
        int m = 1 << p;
        a0 += __shfl_xor(a0, m, 64);
        a1 += __shfl_xor(a1, m, 64);
        a2 += __shfl_xor(a2, m, 64);
        a3 += __shfl_xor(a3, m, 64);
      }
      if (kseg == 0) {
        float r  = 1.f / (1.f + __expf(-(br + a0)));
        float z  = 1.f / (1.f + __expf(-(bz + a1)));
        float tv = bnn + a2 + r * (a3 + bn2);
        float nn = 1.f - 2.f / (__expf(2.f * tv) + 1.f);
        float hnew = nn + z * (hprev - nn);
        u64 pw = ((u64)__float_as_uint(hnew) << 32) | (u64)(u32)(s + 1);
        __hip_atomic_store(&hpack[(size_t)nxt * HSZ + myunit], pw,
                           __ATOMIC_RELEASE, __HIP_MEMORY_SCOPE_AGENT);
        out[(size_t)HSZ + (size_t)s * HSZ + myunit] = hnew;
        hprev = hnew;
        if (s == T_TOTAL - 1) out[myunit] = hnew;
      }
      __syncthreads();
    }
    return;
  }

  // ---- FAST path: barrier-free dataflow ----
  // Prologue (wave 0): x[0],x[1] -> banks 0,1; xA=x[2], xB=x[3] issued.
  f32x4 xA{}, xB{};
  if (tid < 64) {
    float4 t0 = *(const float4*)(xs + tid * 4);
    float4 t1 = *(const float4*)(xs + (size_t)ISZ + tid * 4);
    *(float4*)&x_lds[0][XS2(tid * 4)] = t0;
    *(float4*)&x_lds[1][XS2(tid * 4)] = t1;
    xA = xload_asm(xs + (size_t)2 * ISZ + tid * 4);
    xB = xload_asm(xs + (size_t)3 * ISZ + tid * 4);
  }
  __syncthreads();  // prologue only

  int sticky = 0;

#define POLL8(INV)                                                             \
  asm volatile(INV                                                             \
               "global_load_dwordx4 %0, %8, off offset:0   sc0 nt\n\t"         \
               "global_load_dwordx4 %1, %8, off offset:16  sc0 nt\n\t"         \
               "global_load_dwordx4 %2, %8, off offset:32  sc0 nt\n\t"         \
               "global_load_dwordx4 %3, %8, off offset:48  sc0 nt\n\t"         \
               "global_load_dwordx4 %4, %8, off offset:64  sc0 nt\n\t"         \
               "global_load_dwordx4 %5, %8, off offset:80  sc0 nt\n\t"         \
               "global_load_dwordx4 %6, %8, off offset:96  sc0 nt\n\t"         \
               "global_load_dwordx4 %7, %8, off offset:112 sc0 nt"             \
               : "=&v"(q0), "=&v"(q1), "=&v"(q2), "=&v"(q3),                   \
                 "=&v"(q4), "=&v"(q5), "=&v"(q6), "=&v"(q7)                    \
               : "v"(pbase)                                                    \
               : "memory")
#define CHK(Q) bad |= (Q[0] ^ sv) | (Q[2] ^ sv)
#define MACC(Q, I)                                                             \
  { float v0 = __uint_as_float(Q[1]), v1 = __uint_as_float(Q[3]);              \
    a0 += wh0[2*I] * v0 + wh0[2*I+1] * v1;                                     \
    a1 += wh1[2*I] * v0 + wh1[2*I+1] * v1;                                     \
    a3 += wh2[2*I] * v0 + wh2[2*I+1] * v1; }

  for (int s = 0; s < T_TOTAL; ++s) {
    const u32 sv = (u32)s;
    // Per-thread line: block kseg's 16 {tag,val} pairs, parity s&1.
    const u64* pbase = hpack + (size_t)(s & 1) * HSZ + 16 * kseg;

    // 1) Issue poll round (no wait) — RTT hides under ig-dots.
    u32x4 q0, q1, q2, q3, q4, q5, q6, q7;
    POLL8("");

    // 2) Input-side gate dots from x_lds[s&3].
    float a0 = 0.f, a1 = 0.f, a2 = 0.f, a3 = 0.f;
    {
      const float* xb = x_lds[s & 3];
#pragma unroll
      for (int u = 0; u < 2; ++u) {
        float4 xv = *(const float4*)&xb[XS2(kseg * 8 + u * 4)];
        a0 += wi0[u*4+0]*xv.x + wi0[u*4+1]*xv.y + wi0[u*4+2]*xv.z + wi0[u*4+3]*xv.w;
        a1 += wi1[u*4+0]*xv.x + wi1[u*4+1]*xv.y + wi1[u*4+2]*xv.z + wi1[u*4+3]*xv.w;
        a2 += wi2[u*4+0]*xv.x + wi2[u*4+1]*xv.y + wi2[u*4+2]*xv.z + wi2[u*4+3]*xv.w;
      }
    }

    // 3) Complete detection: all 16 tags (full 32-bit) must equal s.
    asm volatile("s_waitcnt vmcnt(0)" ::: "memory");
    {
      int rounds = 0;
      for (;;) {
        u32 bad = 0;
        CHK(q0); CHK(q1); CHK(q2); CHK(q3);
        CHK(q4); CHK(q5); CHK(q6); CHK(q7);
        if (bad == 0) break;
        if (--budget <= 0) break;
        if (!sticky) {
          if (++rounds >= 64) sticky = 1;
          POLL8("");
          asm volatile("s_waitcnt vmcnt(0)" ::: "memory");
        } else {  // R14-proven: whole-vL1 invalidate before the round
          POLL8("buffer_inv\n\ts_waitcnt vmcnt(0)\n\t");
          asm volatile("s_waitcnt vmcnt(0)" ::: "memory");
        }
      }
    }

    // 4) Wave 0: commit x[s+2] (reg drained by this step's vmcnt(0)),
    //    then issue x[s+4] into the freed reg.
    if (tid < 64) {
      int srow = (s + 4 < T_TOTAL) ? (s + 4) : (T_TOTAL - 1);
      if ((s & 1) == 0) {
        *(f32x4*)&x_lds[(s + 2) & 3][XS2(tid * 4)] = xA;
        xA = xload_asm(xs + (size_t)srow * ISZ + tid * 4);
      } else {
        *(f32x4*)&x_lds[(s + 2) & 3][XS2(tid * 4)] = xB;
        xB = xload_asm(xs + (size_t)srow * ISZ + tid * 4);
      }
    }

    // 5) Hidden-side dots straight from poll registers (no LDS, no barrier).
    MACC(q0, 0); MACC(q1, 1); MACC(q2, 2); MACC(q3, 3);
    MACC(q4, 4); MACC(q5, 5); MACC(q6, 6); MACC(q7, 7);

    // 6) Butterfly over the 32 kseg lanes.
#pragma unroll
    for (int p = 0; p < 5; ++p) {
      int m = 1 << p;
      a0 += __shfl_xor(a0, m, 64);
      a1 += __shfl_xor(a1, m, 64);
      a2 += __shfl_xor(a2, m, 64);
      a3 += __shfl_xor(a3, m, 64);
    }

    // 7) Epilogue + publish on kseg0 lanes. lgkmcnt(0) fences wave-0's x
    //    commit before the publish becomes visible.
    if (kseg == 0) {
      float r  = 1.f / (1.f + __expf(-(br + a0)));
      float z  = 1.f / (1.f + __expf(-(bz + a1)));
      float tv = bnn + a2 + r * (a3 + bn2);
      float nn = 1.f - 2.f / (__expf(2.f * tv) + 1.f);  // tanh, exact limits
      float hnew = nn + z * (hprev - nn);
      hprev = hnew;
      u64 pw = ((u64)__float_as_uint(hnew) << 32) | (u64)(u32)(s + 1);
      u64* pp = hpack + (size_t)((s + 1) & 1) * HSZ + myunit;
      asm volatile("s_waitcnt lgkmcnt(0)\n\t"
                   "global_store_dwordx2 %0, %1, off"
                   :: "v"(pp), "v"(pw) : "memory");
      out[(size_t)HSZ + (size_t)s * HSZ + myunit] = hnew;
      if (s == T_TOTAL - 1) out[myunit] = hnew;
    }
  }
#undef POLL8
#undef CHK
#undef MACC
}

// ---------------------------------------------------------------------------
extern "C" void kernel_launch(void* const* d_in, const int* in_sizes, int n_in,
                              void* d_out, int out_size, void* d_ws, size_t ws_size,
                              hipStream_t stream) {
  const float* xs     = (const float*)d_in[0];
  const float* w_ih   = (const float*)d_in[1];
  const float* w_hh   = (const float*)d_in[2];
  const float* bias   = (const float*)d_in[3];
  const float* bias_n = (const float*)d_in[4];
  float* out = (float*)d_out;

  u64* hpack = (u64*)d_ws;                      // [2][512] {tag,val} = 8 KB
  Ctl* ctl   = (Ctl*)((char*)d_ws + 8192);      // election control

  hipMemsetAsync(d_ws, 0, 8192 + 256, stream);  // tag 0 = step 0, h_0 = 0
  gru_fused<<<256, NTHR, 0, stream>>>(xs, w_ih, w_hh, bias, bias_n,
                                      hpack, ctl, out);
}

// Round 23
// 93526.685 us; speedup vs baseline: 2.9974x; 2.9974x over previous
//
#include <hip/hip_runtime.h>
#include <stdint.h>

typedef unsigned long long u64;
typedef float f32x32 __attribute__((ext_vector_type(32)));
typedef float f32x16 __attribute__((ext_vector_type(16)));
typedef float f32x4  __attribute__((ext_vector_type(4)));

#define T_TOTAL 65536
#define ISZ 256
#define HSZ 512
#define NWORK 16
#define SLICE 32   // HSZ / NWORK
#define NTHR 512   // 8 waves: even 2/SIMD split -> 256-reg budget (R10 lesson)

// LDS skew (word index): +4 words per row -> max 2-way bank aliasing (free).
__device__ __forceinline__ int HSW(int i) { return i + ((i >> 5) << 2); }  // rows of 32
__device__ __forceinline__ int XSW(int i) { return i + ((i >> 4) << 2); }  // rows of 16

struct Ctl { int grank; int chosen; int fastctr; int done; int slowctr; int pad[11]; };

// Publish: PLAIN 8B store (write-through vL1 -> XCD L2). R14/R20-proven.
__device__ __forceinline__ void publish_store(u64* p, u64 v) {
  asm volatile("global_store_dwordx2 %0, %1, off" :: "v"(p), "v"(v) : "memory");
}

// Poll: nt-only L2 load (R20-proven coherent & fast; zero sticky engagement
// observed). Sticky fallback -> R8-proven sc0 RMW poll after 24 stale rounds.
__device__ __forceinline__ u64 poll1_hybrid(u64* p, unsigned sv,
                                            long long& budget, int& sticky) {
  u64 q;
  if (!sticky) {
    for (int i = 0; i < 24; ++i) {
      asm volatile("global_load_dwordx2 %0, %1, off sc0 nt\n\t"
                   "s_waitcnt vmcnt(0)"
                   : "=&v"(q) : "v"(p) : "memory");
      if ((unsigned)(q >> 32) == sv) return q;
    }
    sticky = 1;
  }
  u64 zero = 0;
  for (;;) {
    asm volatile("global_atomic_add_x2 %0, %1, %2, off sc0\n\t"
                 "s_waitcnt vmcnt(0)"
                 : "=&v"(q) : "v"(p), "v"(zero) : "memory");
    if ((unsigned)(q >> 32) == sv) break;
    if (--budget <= 0) break;
  }
  return q;
}

__device__ __forceinline__ f32x4 xload_asm(const float* p) {
  f32x4 r;
  asm volatile("global_load_dwordx4 %0, %1, off" : "=v"(r) : "v"(p));
  return r;
}

// ---------------------------------------------------------------------------
// Persistent fused GRU scan, 16 blocks x 512 threads — R20 shell (best
// structure found across 9 probes) + QUEUE HYGIENE:
//  (1) x[s+2] load ISSUED in the post-detect window (was: pre-poll). At the
//      next step's poll vmcnt(0) it is ~1 full step (~1400cy) old -> retired.
//      R20 issued it ~100cy before the poll, so wave 0's vmcnt(0) ate up to a
//      full HBM latency each step and the barrier spread it to all waves.
//  (2) FAST-mode barrier = raw s_barrier + lgkmcnt(0) only. R20's
//      __syncthreads drained seg0's fresh out[]-HBM store (~600cy) on the
//      chain; now those stores drain at the NEXT step's poll (~1 step old).
//
// Ordering safety (fast mode, one lgkm-barrier B per step):
//  - h_lds parity: writer at s+2 (post-detect(s+2)) overwrites h_lds[s&1].
//    detect(s+2) => all 512 publishes of tag s+2 => every publishing wave
//    finished matvec(s+1) => passed B(s+1) => (block barrier) ALL waves of
//    this block passed B(s+1) => program order: their matvec(s) reads of
//    h_lds[s&1] are complete. No overlap.
//  - x_lds parity: commit@s (post-detect(s), pre-B(s)) writes bank (s+1)&1;
//    readers at s+1 (ig-dots, post-B(s)) see it via lgkmcnt(0)+B(s). Next
//    commit to that bank at s+2 is post-detect(s+2) => all waves finished
//    ig-dots(s+1) (program order: ig-dots(s+1) < matvec(s+1) < publish(s+2)).
//  - h_lds poll-write@s -> readers@s: lgkmcnt(0) before B(s) completes it.
//  - Inter-block slot ring: R6/R8 tag-gating argument unchanged.
// Spin fuse (fail visibly, never wedge); SLOW fallback: R2-proven protocol
// with full __syncthreads and compiler-managed x loads.
// ---------------------------------------------------------------------------
__global__ __launch_bounds__(NTHR, 1) void gru_fused(
    const float* __restrict__ xs, const float* __restrict__ w_ih,
    const float* __restrict__ w_hh, const float* __restrict__ bias,
    const float* __restrict__ bias_n, u64* __restrict__ hslot,
    Ctl* __restrict__ ctl, float* __restrict__ out) {
  const int tid = threadIdx.x;
  const int seg = tid & 15;   // K-segment: h[32*seg..+32), x[16*seg..+16)
  const int rg  = tid >> 4;   // unit within slice (0..31)

  __shared__ int s_role, s_fast;
  __shared__ __align__(16) float x_lds[2][320];
  __shared__ __align__(16) float h_lds[2][576];

  // ---- election: verify 16 blocks on one XCD, else agent-scope fallback
  if (tid == 0) {
    unsigned xcc = 0;
    asm volatile("s_getreg_b32 %0, hwreg(HW_REG_XCC_ID)" : "=s"(xcc));
    long long eb = 100000000;
    int rank = __hip_atomic_fetch_add(&ctl->grank, 1, __ATOMIC_RELAXED,
                                      __HIP_MEMORY_SCOPE_AGENT);
    if (rank == 0)
      __hip_atomic_store(&ctl->chosen, (int)xcc + 1, __ATOMIC_RELEASE,
                         __HIP_MEMORY_SCOPE_AGENT);
    int chosen;
    do { chosen = __hip_atomic_load(&ctl->chosen, __ATOMIC_ACQUIRE,
                                    __HIP_MEMORY_SCOPE_AGENT); }
    while (chosen == 0 && --eb > 0);
    int fr = -1;
    if ((int)xcc == chosen - 1)
      fr = __hip_atomic_fetch_add(&ctl->fastctr, 1, __ATOMIC_RELAXED,
                                  __HIP_MEMORY_SCOPE_AGENT);
    __hip_atomic_fetch_add(&ctl->done, 1, __ATOMIC_ACQ_REL,
                           __HIP_MEMORY_SCOPE_AGENT);
    int dn;
    do { dn = __hip_atomic_load(&ctl->done, __ATOMIC_ACQUIRE,
                                __HIP_MEMORY_SCOPE_AGENT); }
    while (dn < (int)gridDim.x && --eb > 0);
    int fc = __hip_atomic_load(&ctl->fastctr, __ATOMIC_ACQUIRE,
                               __HIP_MEMORY_SCOPE_AGENT);
    int fast = (fc >= NWORK && dn >= (int)gridDim.x) ? 1 : 0;
    int role = -1;
    if (fast) {
      if (fr >= 0 && fr < NWORK) role = fr;
    } else {
      int sr = __hip_atomic_fetch_add(&ctl->slowctr, 1, __ATOMIC_RELAXED,
                                      __HIP_MEMORY_SCOPE_AGENT);
      if (sr < NWORK) role = sr;
    }
    s_role = role; s_fast = fast;
  }
  __syncthreads();
  const int role = s_role;   // uniform per block
  const int fast = s_fast;
  if (role < 0) return;      // whole block exits together

  // ---- weights into registers (ext_vector, static indexing; R8-proven) ----
  const int myunit = role * SLICE + rg;
  f32x32 wh0, wh1, wh2;
  f32x16 wi0, wi1, wi2;
  {
    const float* h0 = w_hh + (size_t)(0 * HSZ + myunit) * HSZ + seg * 32;
    const float* h1 = w_hh + (size_t)(1 * HSZ + myunit) * HSZ + seg * 32;
    const float* h2 = w_hh + (size_t)(2 * HSZ + myunit) * HSZ + seg * 32;
#pragma unroll
    for (int u = 0; u < 8; ++u) {
      float4 a = *(const float4*)(h0 + u * 4);
      float4 b = *(const float4*)(h1 + u * 4);
      float4 c = *(const float4*)(h2 + u * 4);
      wh0[u*4+0]=a.x; wh0[u*4+1]=a.y; wh0[u*4+2]=a.z; wh0[u*4+3]=a.w;
      wh1[u*4+0]=b.x; wh1[u*4+1]=b.y; wh1[u*4+2]=b.z; wh1[u*4+3]=b.w;
      wh2[u*4+0]=c.x; wh2[u*4+1]=c.y; wh2[u*4+2]=c.z; wh2[u*4+3]=c.w;
    }
    const float* i0 = w_ih + (size_t)(0 * HSZ + myunit) * ISZ + seg * 16;
    const float* i1 = w_ih + (size_t)(1 * HSZ + myunit) * ISZ + seg * 16;
    const float* i2 = w_ih + (size_t)(2 * HSZ + myunit) * ISZ + seg * 16;
#pragma unroll
    for (int u = 0; u < 4; ++u) {
      float4 a = *(const float4*)(i0 + u * 4);
      float4 b = *(const float4*)(i1 + u * 4);
      float4 c = *(const float4*)(i2 + u * 4);
      wi0[u*4+0]=a.x; wi0[u*4+1]=a.y; wi0[u*4+2]=a.z; wi0[u*4+3]=a.w;
      wi1[u*4+0]=b.x; wi1[u*4+1]=b.y; wi1[u*4+2]=b.z; wi1[u*4+3]=b.w;
      wi2[u*4+0]=c.x; wi2[u*4+1]=c.y; wi2[u*4+2]=c.z; wi2[u*4+3]=c.w;
    }
  }
  const float br  = bias[myunit];
  const float bz  = bias[HSZ + myunit];
  const float bnn = bias[2 * HSZ + myunit];
  const float bn2 = bias_n[myunit];

  // prologue: x[0] -> LDS buf0; xreg = x[1] (committed to buf1 at step 0).
  f32x4 xreg{};
  if (tid < 64) {
    float4 t0 = *(const float4*)(xs + tid * 4);
    *(float4*)&x_lds[0][XSW(tid * 4)] = t0;
    if (fast) {
      xreg = xload_asm(xs + (size_t)ISZ + tid * 4);
    } else {
      float4 t1 = *(const float4*)(xs + (size_t)ISZ + tid * 4);
      xreg[0]=t1.x; xreg[1]=t1.y; xreg[2]=t1.z; xreg[3]=t1.w;
    }
  }
  __syncthreads();

  long long budget = 20000000;  // spin fuse (fail visibly, never wedge)
  int sticky = 0;

  for (int s = 0; s < T_TOTAL; ++s) {
    const int cur = s & 1, nxt = cur ^ 1;

    // 1) Input-side gate dots (LDS only). a3 = hidden-side n, separate.
    float a0 = 0.f, a1 = 0.f, a2 = 0.f, a3 = 0.f;
#pragma unroll
    for (int u = 0; u < 4; ++u) {
      float4 xv = *(const float4*)&x_lds[cur][XSW(seg * 16 + u * 4)];
      a0 += wi0[u*4+0]*xv.x + wi0[u*4+1]*xv.y + wi0[u*4+2]*xv.z + wi0[u*4+3]*xv.w;
      a1 += wi1[u*4+0]*xv.x + wi1[u*4+1]*xv.y + wi1[u*4+2]*xv.z + wi1[u*4+3]*xv.w;
      a2 += wi2[u*4+0]*xv.x + wi2[u*4+1]*xv.y + wi2[u*4+2]*xv.z + wi2[u*4+3]*xv.w;
    }

    // 2) Poll h version s (1 slot/thread, 16B padded). Every lane's queue at
    //    this vmcnt(0): only ops >= ~1 step old (x load / pub+out stores) +
    //    this poll load -> genuinely waits one L2 RTT.
    u64* sb = hslot + (size_t)cur * (HSZ * 2);
    u64 q0;
    if (fast) {
      q0 = poll1_hybrid(&sb[2 * tid], (unsigned)s, budget, sticky);
    } else {
      do {
        q0 = __hip_atomic_load(&sb[2 * tid], __ATOMIC_ACQUIRE,
                               __HIP_MEMORY_SCOPE_AGENT);
      } while ((unsigned)(q0 >> 32) != (unsigned)s && --budget > 0);
    }
    h_lds[cur][HSW(tid)] = __uint_as_float((unsigned)q0);

    // 3) Post-detect window: commit x[s+1] (loaded at s-1, drained by the
    //    poll's vmcnt(0)); then ISSUE x[s+2] — it has a full step to retire.
    if (tid < 64) {
      *(f32x4*)&x_lds[nxt][XSW(tid * 4)] = xreg;
      int srow = (s + 2 < T_TOTAL) ? (s + 2) : (T_TOTAL - 1);
      if (fast) {
        xreg = xload_asm(xs + (size_t)srow * ISZ + tid * 4);
      } else {
        float4 t = *(const float4*)(xs + (size_t)srow * ISZ + tid * 4);
        xreg[0]=t.x; xreg[1]=t.y; xreg[2]=t.z; xreg[3]=t.w;
      }
    }

    // B: fast = LDS-only barrier (no vmcnt drain); slow = full barrier.
    if (fast) {
      asm volatile("s_waitcnt lgkmcnt(0)\n\ts_barrier" ::: "memory");
    } else {
      __syncthreads();
    }

    // 4) Hidden-side dots (critical chain): 3 rows x 32-wide segment.
#pragma unroll
    for (int u = 0; u < 8; ++u) {
      float4 hv = *(const float4*)&h_lds[cur][HSW(seg * 32 + u * 4)];
      a0 += wh0[u*4+0]*hv.x + wh0[u*4+1]*hv.y + wh0[u*4+2]*hv.z + wh0[u*4+3]*hv.w;
      a1 += wh1[u*4+0]*hv.x + wh1[u*4+1]*hv.y + wh1[u*4+2]*hv.z + wh1[u*4+3]*hv.w;
      a3 += wh2[u*4+0]*hv.x + wh2[u*4+1]*hv.y + wh2[u*4+2]*hv.z + wh2[u*4+3]*hv.w;
    }
#pragma unroll
    for (int p = 0; p < 4; ++p) {
      int m = 1 << p;
      a0 += __shfl_xor(a0, m, 64);
      a1 += __shfl_xor(a1, m, 64);
      a2 += __shfl_xor(a2, m, 64);
      a3 += __shfl_xor(a3, m, 64);
    }

    // 5) Epilogue + publish (chain edge first), then out store.
    if (seg == 0) {
      float r  = 1.f / (1.f + __expf(-(br + a0)));
      float z  = 1.f / (1.f + __expf(-(bz + a1)));
      float tv = bnn + a2 + r * (a3 + bn2);
      float nn = 1.f - 2.f / (__expf(2.f * tv) + 1.f);  // tanh, exact limits
      float hold = h_lds[cur][HSW(myunit)];
      float hnew = nn + z * (hold - nn);
      u64 pw = ((u64)(unsigned)(s + 1) << 32) | (u64)__float_as_uint(hnew);
      u64* pp = &hslot[(size_t)nxt * (HSZ * 2) + 2 * myunit];
      if (fast)
        publish_store(pp, pw);
      else
        __hip_atomic_store(pp, pw, __ATOMIC_RELEASE, __HIP_MEMORY_SCOPE_AGENT);
      out[(size_t)HSZ + (size_t)s * HSZ + myunit] = hnew;
      if (s == T_TOTAL - 1) out[myunit] = hnew;
    }
  }
}

// ---------------------------------------------------------------------------
extern "C" void kernel_launch(void* const* d_in, const int* in_sizes, int n_in,
                              void* d_out, int out_size, void* d_ws, size_t ws_size,
                              hipStream_t stream) {
  const float* xs     = (const float*)d_in[0];
  const float* w_ih   = (const float*)d_in[1];
  const float* w_hh   = (const float*)d_in[2];
  const float* bias   = (const float*)d_in[3];
  const float* bias_n = (const float*)d_in[4];
  float* out   = (float*)d_out;
  u64*   hslot = (u64*)d_ws;                    // [2][512] padded slots = 16 KB
  Ctl*   ctl   = (Ctl*)((char*)d_ws + 16384);   // election control

  hipMemsetAsync(d_ws, 0, 16384 + 256, stream); // tags=0 => h_0 = 0; ctl = 0
  gru_fused<<<256, NTHR, 0, stream>>>(xs, w_ih, w_hh, bias, bias_n, hslot, ctl, out);
}